// Round 1
// baseline (1373.222 us; speedup 1.0000x reference)
//
#include <hip/hip_runtime.h>

// ---- constants matching the reference's f64->f32 rounding ----
// gamma = 5/3 (python f64), gm1 = gamma-1 (f64), used as weak-typed f32.
#define GAMMA_F  ((float)(5.0/3.0))
#define GM1_F    ((float)(5.0/3.0 - 1.0))
#define G_OVER_GM1_F ((float)((5.0/3.0)/(5.0/3.0 - 1.0)))   // == 2.5f

__device__ __forceinline__ float rcp_fast(float x) { return __builtin_amdgcn_rcpf(x); }

// tanh(x) = 1 - 2/(1+e^{2x}); __expf is v_exp based (~2 ulp), rcp ~1 ulp.
// Absolute error ~1e-7, same scale as fp32 rounding noise.
__device__ __forceinline__ float fast_tanh(float x) {
    float e = __expf(2.0f * x);
    return fmaf(-2.0f, rcp_fast(e + 1.0f), 1.0f);
}

// Relativistic shock jump conditions (Taub adiabat), fp32, mirrors reference.
__device__ __forceinline__ void vel_shock(float pC, float rho, float p, float v, float sign,
                                          float& rhoC, float& hC, float& vstar, float& Vs) {
    float h  = 1.0f + G_OVER_GM1_F * p / rho;
    float W  = 1.0f / sqrtf(1.0f - v * v);
    float dp = p - pC;
    float t  = GM1_F * dp / (GAMMA_F * pC);
    float A  = 1.0f + t;
    float B  = -t;
    float C  = h * dp / rho - h * h;
    float disc = fmaxf(B * B - 4.0f * A * C, 0.0f);
    hC   = (-B + sqrtf(disc)) / (2.0f * A);
    rhoC = GAMMA_F * pC / (GM1_F * (hC - 1.0f));
    float j2 = fmaxf((pC - p) / (h / rho - hC / rhoC), 1e-12f);
    float jabs = sqrtf(j2);
    float rw = rho * W;
    float a2 = rw * rw;
    Vs = (a2 * v + sign * jabs * sqrtf(j2 + a2 * (1.0f - v * v))) / (a2 + j2);
    float Ws = 1.0f / sqrtf(fmaxf(1.0f - Vs * Vs, 1e-12f));
    float js = sign * jabs;
    vstar = (h * W * v + Ws * (pC - p) / js) /
            (h * W + (pC - p) * (Ws * v / js + 1.0f / (rho * W)));
}

__global__ __launch_bounds__(256) void shock_solver_kernel(
    const float* __restrict__ P, const float* __restrict__ F,
    const float* __restrict__ W1, const float* __restrict__ b1,
    const float* __restrict__ W2, const float* __restrict__ b2,
    const float* __restrict__ W3, const float* __restrict__ b3,
    float* __restrict__ out, int N)
{
    int n = blockIdx.x * blockDim.x + threadIdx.x;
    if (n >= N) return;

    // P layout: (N,3,2) -> [rhoL,rhoR,pL,pR,vL,vR]; 24B stride, 8B aligned.
    const float2* P2 = reinterpret_cast<const float2*>(P + (size_t)n * 6);
    float2 c0 = P2[0], c1 = P2[1], c2 = P2[2];
    float rhoL = c0.x, rhoR = c0.y;
    float pL   = c1.x, pR   = c1.y;
    float vL   = c2.x, vR   = c2.y;

    float x0 = logf(rhoL), x1 = logf(rhoR);
    float x2 = logf(pL),   x3 = logf(pR);
    float x4 = vL,         x5 = vR;
    float a  = fmaxf(pL, pR);

    // running argmin-select state (first-min semantics: strict <)
    float bestGap = 0.0f;
    float s_pC = 0.0f, s_rhoCL = 0.0f, s_hCL = 0.0f, s_vstarL = 0.0f, s_VsL = 0.0f;
    float s_rhoCR = 0.0f, s_hCR = 0.0f, s_vstarR = 0.0f, s_VsR = 0.0f;

    #pragma unroll 1
    for (int e = 0; e < 8; ++e) {
        const float* w1  = W1 + e * 6 * 64;
        const float* bb1 = b1 + e * 64;
        const float* w2  = W2 + e * 64 * 64;
        const float* bb2 = b2 + e * 64;
        const float* w3  = W3 + e * 64;

        // ---- layer 1: 6 -> 64, fully unrolled (h1 indices compile-time) ----
        float h1[64];
        #pragma unroll
        for (int i = 0; i < 64; ++i) {
            float acc = bb1[i];
            acc = fmaf(x0, w1[0 * 64 + i], acc);
            acc = fmaf(x1, w1[1 * 64 + i], acc);
            acc = fmaf(x2, w1[2 * 64 + i], acc);
            acc = fmaf(x3, w1[3 * 64 + i], acc);
            acc = fmaf(x4, w1[4 * 64 + i], acc);
            acc = fmaf(x5, w1[5 * 64 + i], acc);
            h1[i] = fast_tanh(acc);
        }

        // ---- layer 2 (64->64) fused with layer 3 (64->1) ----
        // j-chunks of 16 so h2 never materializes; k fully unrolled so all
        // h1[] / acc[] indices are compile-time constants (no scratch).
        float z3 = b3[e];
        #pragma unroll 1
        for (int j0 = 0; j0 < 64; j0 += 16) {
            float acc[16];
            #pragma unroll
            for (int j = 0; j < 16; ++j) acc[j] = bb2[j0 + j];
            #pragma unroll
            for (int k = 0; k < 64; ++k) {
                const float* w = w2 + k * 64 + j0;
                float hk = h1[k];
                #pragma unroll
                for (int j = 0; j < 16; ++j) acc[j] = fmaf(hk, w[j], acc[j]);
            }
            #pragma unroll
            for (int j = 0; j < 16; ++j)
                z3 = fmaf(fast_tanh(acc[j]), w3[j0 + j], z3);
        }

        float xi = rcp_fast(1.0f + __expf(-z3));
        float pC = a * (1.0f + xi) / (1.0f - xi);

        float rhoCL, hCL, vstarL, VsL;
        vel_shock(pC, rhoL, pL, vL, -1.0f, rhoCL, hCL, vstarL, VsL);
        float rhoCR, hCR, vstarR, VsR;
        vel_shock(pC, rhoR, pR, vR, +1.0f, rhoCR, hCR, vstarR, VsR);

        float gap = fabsf(vstarL - vstarR);
        if (e == 0 || gap < bestGap) {
            bestGap = gap;
            s_pC = pC;
            s_rhoCL = rhoCL; s_hCL = hCL; s_vstarL = vstarL; s_VsL = VsL;
            s_rhoCR = rhoCR; s_hCR = hCR; s_vstarR = vstarR; s_VsR = VsR;
        }
    }

    // ---- final flux assembly ----
    float lambdaC = 0.5f * (s_vstarR + s_vstarL);
    float WC = 1.0f / sqrtf(1.0f - lambdaC * lambdaC);
    float densCL = WC * s_rhoCL;
    float densCR = WC * s_rhoCR;
    float momCL = WC * WC * s_rhoCL * s_hCL * lambdaC;
    float momCR = WC * WC * s_rhoCR * s_hCR * lambdaC;

    float FCL0 = densCL * lambdaC;
    float FCL1 = densCL * (WC * s_hCL - 1.0f) * lambdaC;
    float FCL2 = momCL * lambdaC + s_pC;
    float FCR0 = densCR * lambdaC;
    float FCR1 = densCR * (WC * s_hCR - 1.0f) * lambdaC;
    float FCR2 = momCR * lambdaC + s_pC;

    // F layout: (N,3,2)
    const float2* F2 = reinterpret_cast<const float2*>(F + (size_t)n * 6);
    float2 f0p = F2[0], f1p = F2[1], f2p = F2[2];

    float f0 = 0.0f, f1 = 0.0f, f2 = 0.0f;
    // jnp.where chain: later masks override -> apply in reference order.
    if (s_VsL >= 0.0f)                       { f0 = f0p.x; f1 = f1p.x; f2 = f2p.x; }
    if (s_VsL < 0.0f && lambdaC > 0.0f)      { f0 = FCL0;  f1 = FCL1;  f2 = FCL2; }
    if (lambdaC <= 0.0f && s_VsR > 0.0f)     { f0 = FCR0;  f1 = FCR1;  f2 = FCR2; }
    if (s_VsR <= 0.0f)                       { f0 = f0p.y; f1 = f1p.y; f2 = f2p.y; }

    out[(size_t)n * 3 + 0] = f0;
    out[(size_t)n * 3 + 1] = f1;
    out[(size_t)n * 3 + 2] = f2;
}

extern "C" void kernel_launch(void* const* d_in, const int* in_sizes, int n_in,
                              void* d_out, int out_size, void* d_ws, size_t ws_size,
                              hipStream_t stream) {
    const float* P  = (const float*)d_in[0];
    // d_in[1] = U (unused), d_in[3] = cmax (unused), d_in[4] = cmin (unused)
    const float* F  = (const float*)d_in[2];
    const float* W1 = (const float*)d_in[5];
    const float* b1 = (const float*)d_in[6];
    const float* W2 = (const float*)d_in[7];
    const float* b2 = (const float*)d_in[8];
    const float* W3 = (const float*)d_in[9];
    const float* b3 = (const float*)d_in[10];
    float* out = (float*)d_out;

    int N = in_sizes[0] / 6;
    int grid = (N + 255) / 256;
    shock_solver_kernel<<<grid, 256, 0, stream>>>(P, F, W1, b1, W2, b2, W3, b3, out, N);
}

// Round 2
// 786.176 us; speedup vs baseline: 1.7467x; 1.7467x over previous
//
#include <hip/hip_runtime.h>

typedef short v8s __attribute__((ext_vector_type(8)));   // 8 bf16 (4 VGPRs) MFMA frag
typedef float v4f __attribute__((ext_vector_type(4)));   // 4 f32 MFMA acc

#define GAMMA_F       ((float)(5.0/3.0))
#define GM1_F         ((float)(5.0/3.0 - 1.0))
#define G_OVER_GM1_F  2.5f

__device__ __forceinline__ float rcp_f(float x){ return __builtin_amdgcn_rcpf(x); }
__device__ __forceinline__ float rsq_f(float x){ return __builtin_amdgcn_rsqf(x); }
__device__ __forceinline__ float fdiv(float a, float b){ return a * __builtin_amdgcn_rcpf(b); }

// tanh(x) = 1 - 2/(1+e^{2x}) ; ~2 ulp, under split-bf16 noise floor
__device__ __forceinline__ float fast_tanh(float x){
    float e = __expf(2.0f * x);
    return fmaf(-2.0f, rcp_f(e + 1.0f), 1.0f);
}

// float -> bf16 bits, round-to-nearest-even
__device__ __forceinline__ unsigned bfbits(float f){
    unsigned u = __builtin_bit_cast(unsigned, f);
    return (u + 0x7FFFu + ((u >> 16) & 1u)) >> 16;
}
// split f = hi + lo (two bf16), ~17 mantissa bits total
__device__ __forceinline__ void split2(float f, unsigned& hi, unsigned& lo){
    hi = bfbits(f);
    float fh = __builtin_bit_cast(float, hi << 16);
    lo = bfbits(f - fh);
}

// Relativistic shock jump conditions (Taub adiabat), fp32 + fast rcp/rsq.
__device__ __forceinline__ void vel_shock(float pC, float rho, float p, float v, float sign,
                                          float& rhoC, float& hC, float& vstar, float& Vs){
    float h  = fmaf(G_OVER_GM1_F, fdiv(p, rho), 1.0f);
    float W  = rsq_f(1.0f - v * v);
    float dp = p - pC;
    float t  = fdiv(GM1_F * dp, GAMMA_F * pC);
    float A  = 1.0f + t;
    float B  = -t;
    float C  = fdiv(h * dp, rho) - h * h;
    float disc = fmaxf(B * B - 4.0f * A * C, 0.0f);
    hC   = fdiv(-B + sqrtf(disc), 2.0f * A);
    rhoC = fdiv(GAMMA_F * pC, GM1_F * (hC - 1.0f));
    float j2 = fmaxf(fdiv(pC - p, fdiv(h, rho) - fdiv(hC, rhoC)), 1e-12f);
    float jabs = sqrtf(j2);
    float rw = rho * W;
    float a2 = rw * rw;
    Vs = fdiv(a2 * v + sign * jabs * sqrtf(j2 + a2 * (1.0f - v * v)), a2 + j2);
    float Ws = rsq_f(fmaxf(1.0f - Vs * Vs, 1e-12f));
    float js = sign * jabs;
    vstar = fdiv(h * W * v + fdiv(Ws * (pC - p), js),
                 h * W + (pC - p) * (fdiv(Ws * v, js) + rcp_f(rho * W)));
}

// One wave (64 threads) owns 64 cells. Per ensemble e:
//   L1: z1[j][c] via mfma_16x16x32 (A=W1^T split-bf16, B=x split-bf16, K padded 6->32)
//   tanh -> split -> LDS (XOR-swizzled, wave-private, no barriers)
//   L2: z2[j][c] via mfma (A=W2^T, B=h1 from LDS), K=64 (2 steps), bias as C-init
//   L3: per-lane dot(16 j's) + shfl_xor reduce over the 4 lane-groups
//   physics + running argmin per lane (lane l <-> cell base+l)
__global__ __launch_bounds__(64, 2) void shock_mfma_kernel(
    const float* __restrict__ P, const float* __restrict__ F,
    const float* __restrict__ W1, const float* __restrict__ b1,
    const float* __restrict__ W2, const float* __restrict__ b2,
    const float* __restrict__ W3, const float* __restrict__ b3,
    float* __restrict__ out, int N)
{
    __shared__ unsigned short h1hi[64 * 64];   // [cell][k] bf16 hi, k XOR-swizzled
    __shared__ unsigned short h1lo[64 * 64];   // [cell][k] bf16 lo

    const int l = threadIdx.x;        // lane 0..63
    const int g = l >> 4;             // lane group 0..3
    const int q = l & 15;             // lane-in-group
    const int n  = blockIdx.x * 64 + l;
    const int nc = (n < N) ? n : (N - 1);

    // P layout (N,3,2): [rhoL,rhoR,pL,pR,vL,vR]
    const float2* P2 = reinterpret_cast<const float2*>(P + (size_t)nc * 6);
    float2 c0 = P2[0], c1 = P2[1], c2 = P2[2];
    float rhoL = c0.x, rhoR = c0.y;
    float pL   = c1.x, pR   = c1.y;
    float vL   = c2.x, vR   = c2.y;

    float x0 = __logf(rhoL), x1 = __logf(rhoR);
    float x2 = __logf(pL),   x3 = __logf(pR);
    float aP = fmaxf(pL, pR);

    // pack this lane's x (its own cell) as bf16 hi/lo pairs, k-slots 0..7 (6,7 zero)
    unsigned xh[4], xl[4];
    {
        unsigned h0, l0, h1_, l1_;
        split2(x0, h0, l0); split2(x1, h1_, l1_); xh[0] = h0 | (h1_ << 16); xl[0] = l0 | (l1_ << 16);
        split2(x2, h0, l0); split2(x3, h1_, l1_); xh[1] = h0 | (h1_ << 16); xl[1] = l0 | (l1_ << 16);
        split2(vL, h0, l0); split2(vR, h1_, l1_); xh[2] = h0 | (h1_ << 16); xl[2] = l0 | (l1_ << 16);
        xh[3] = 0u; xl[3] = 0u;
    }

    // x B-frags per cell-tile (ensemble-invariant): lane l supplies B[k=8g+jj][cell=16ct+q]
    // only g==0 carries data (k<8); rest of K is zero padding.
    v8s xbh[4], xbl[4];
    #pragma unroll
    for (int ct = 0; ct < 4; ++ct){
        int src = 16 * ct + q;
        #pragma unroll
        for (int w = 0; w < 4; ++w){
            unsigned vh = (unsigned)__shfl((int)xh[w], src, 64);
            unsigned vl = (unsigned)__shfl((int)xl[w], src, 64);
            if (g != 0){ vh = 0u; vl = 0u; }
            xbh[ct][2*w]   = (short)(vh & 0xFFFFu);
            xbh[ct][2*w+1] = (short)(vh >> 16);
            xbl[ct][2*w]   = (short)(vl & 0xFFFFu);
            xbl[ct][2*w+1] = (short)(vl >> 16);
        }
    }

    // running argmin-select state (first-min: strict <)
    float bestGap = 0.0f;
    float s_pC = 0.0f, s_rhoCL = 0.0f, s_hCL = 0.0f, s_vstarL = 0.0f, s_VsL = 0.0f;
    float s_rhoCR = 0.0f, s_hCR = 0.0f, s_vstarR = 0.0f, s_VsR = 0.0f;

    #pragma unroll 1
    for (int e = 0; e < 8; ++e){
        const float* w1 = W1 + e * 6 * 64;
        const float* w2 = W2 + e * 64 * 64;

        // ---- W1^T A-frags: lane l holds A[row=16mt+q][k=8g+jj] = W1[k][16mt+q]
        v8s a1h[4], a1l[4];
        #pragma unroll
        for (int mt = 0; mt < 4; ++mt){
            #pragma unroll
            for (int jj = 0; jj < 8; ++jj){ a1h[mt][jj] = 0; a1l[mt][jj] = 0; }
            if (g == 0){
                #pragma unroll
                for (int jj = 0; jj < 6; ++jj){
                    float wv = w1[jj * 64 + 16 * mt + q];
                    unsigned hb, lb; split2(wv, hb, lb);
                    a1h[mt][jj] = (short)hb; a1l[mt][jj] = (short)lb;
                }
            }
        }

        // ---- L1: D1[mt][ct], rows j=16mt+4g+r, cols cell=16ct+q; C-init = b1
        v4f D1[4][4];
        #pragma unroll
        for (int mt = 0; mt < 4; ++mt){
            v4f bias = *reinterpret_cast<const v4f*>(b1 + e * 64 + 16 * mt + 4 * g);
            #pragma unroll
            for (int ct = 0; ct < 4; ++ct){
                v4f d = bias;
                d = __builtin_amdgcn_mfma_f32_16x16x32_bf16(a1h[mt], xbh[ct], d, 0, 0, 0);
                d = __builtin_amdgcn_mfma_f32_16x16x32_bf16(a1h[mt], xbl[ct], d, 0, 0, 0);
                d = __builtin_amdgcn_mfma_f32_16x16x32_bf16(a1l[mt], xbh[ct], d, 0, 0, 0);
                D1[mt][ct] = d;
            }
        }

        // ---- tanh + split + swizzled LDS write (wave-private; no barrier needed)
        #pragma unroll
        for (int mt = 0; mt < 4; ++mt){
            #pragma unroll
            for (int ct = 0; ct < 4; ++ct){
                int c  = 16 * ct + q;
                int j0 = 16 * mt + 4 * g;
                unsigned hb[4], lb[4];
                #pragma unroll
                for (int r = 0; r < 4; ++r){
                    float t = fast_tanh(D1[mt][ct][r]);
                    split2(t, hb[r], lb[r]);
                }
                int idx = c * 64 + (j0 ^ ((c & 7) << 3));   // element-index XOR swizzle
                *reinterpret_cast<uint2*>(&h1hi[idx]) = make_uint2(hb[0] | (hb[1] << 16), hb[2] | (hb[3] << 16));
                *reinterpret_cast<uint2*>(&h1lo[idx]) = make_uint2(lb[0] | (lb[1] << 16), lb[2] | (lb[3] << 16));
            }
        }

        // ---- L2: K=64 in 2 steps; A=W2^T frags built on the fly; B from LDS
        v4f D2[4][4];
        #pragma unroll
        for (int mt = 0; mt < 4; ++mt){
            v4f bias2 = *reinterpret_cast<const v4f*>(b2 + e * 64 + 16 * mt + 4 * g);
            #pragma unroll
            for (int ct = 0; ct < 4; ++ct) D2[mt][ct] = bias2;
        }
        #pragma unroll
        for (int ks = 0; ks < 2; ++ks){
            v8s bh[4], bl[4];
            #pragma unroll
            for (int ct = 0; ct < 4; ++ct){
                int c   = 16 * ct + q;
                int k0  = 8 * g + 32 * ks;
                int idx = c * 64 + (k0 ^ ((c & 7) << 3));
                bh[ct] = *reinterpret_cast<const v8s*>(&h1hi[idx]);
                bl[ct] = *reinterpret_cast<const v8s*>(&h1lo[idx]);
            }
            #pragma unroll
            for (int mt = 0; mt < 4; ++mt){
                v8s a2h, a2l;
                #pragma unroll
                for (int jj = 0; jj < 8; ++jj){
                    float wv = w2[(8 * g + 32 * ks + jj) * 64 + 16 * mt + q];
                    unsigned hb, lb; split2(wv, hb, lb);
                    a2h[jj] = (short)hb; a2l[jj] = (short)lb;
                }
                #pragma unroll
                for (int ct = 0; ct < 4; ++ct){
                    v4f d = D2[mt][ct];
                    d = __builtin_amdgcn_mfma_f32_16x16x32_bf16(a2h, bh[ct], d, 0, 0, 0);
                    d = __builtin_amdgcn_mfma_f32_16x16x32_bf16(a2h, bl[ct], d, 0, 0, 0);
                    d = __builtin_amdgcn_mfma_f32_16x16x32_bf16(a2l, bh[ct], d, 0, 0, 0);
                    D2[mt][ct] = d;
                }
            }
        }

        // ---- L3: per-lane partial dot over its 16 rows, reduce over lane-groups
        float z[4] = {0.f, 0.f, 0.f, 0.f};
        #pragma unroll
        for (int mt = 0; mt < 4; ++mt){
            v4f w3v = *reinterpret_cast<const v4f*>(W3 + e * 64 + 16 * mt + 4 * g);
            #pragma unroll
            for (int ct = 0; ct < 4; ++ct){
                #pragma unroll
                for (int r = 0; r < 4; ++r)
                    z[ct] = fmaf(fast_tanh(D2[mt][ct][r]), w3v[r], z[ct]);
            }
        }
        #pragma unroll
        for (int ct = 0; ct < 4; ++ct){
            z[ct] += __shfl_xor(z[ct], 16, 64);
            z[ct] += __shfl_xor(z[ct], 32, 64);
        }
        // lane l's own cell is ct = g
        float zown = (g == 0) ? z[0] : (g == 1) ? z[1] : (g == 2) ? z[2] : z[3];
        float z3 = zown + b3[e];
        // (1+sigmoid(z))/(1-sigmoid(z)) == 1 + 2*e^z
        float pC = aP * fmaf(2.0f, __expf(z3), 1.0f);

        float rhoCL, hCL, vstarL, VsL, rhoCR, hCR, vstarR, VsR;
        vel_shock(pC, rhoL, pL, vL, -1.0f, rhoCL, hCL, vstarL, VsL);
        vel_shock(pC, rhoR, pR, vR, +1.0f, rhoCR, hCR, vstarR, VsR);

        float gap = fabsf(vstarL - vstarR);
        bool take = (e == 0) || (gap < bestGap);
        if (take){
            bestGap = gap; s_pC = pC;
            s_rhoCL = rhoCL; s_hCL = hCL; s_vstarL = vstarL; s_VsL = VsL;
            s_rhoCR = rhoCR; s_hCR = hCR; s_vstarR = vstarR; s_VsR = VsR;
        }
    }

    if (n < N){
        float lambdaC = 0.5f * (s_vstarR + s_vstarL);
        float WC = rsq_f(1.0f - lambdaC * lambdaC);
        float densCL = WC * s_rhoCL;
        float densCR = WC * s_rhoCR;
        float momCL = WC * WC * s_rhoCL * s_hCL * lambdaC;
        float momCR = WC * WC * s_rhoCR * s_hCR * lambdaC;

        float FCL0 = densCL * lambdaC;
        float FCL1 = densCL * (WC * s_hCL - 1.0f) * lambdaC;
        float FCL2 = momCL * lambdaC + s_pC;
        float FCR0 = densCR * lambdaC;
        float FCR1 = densCR * (WC * s_hCR - 1.0f) * lambdaC;
        float FCR2 = momCR * lambdaC + s_pC;

        const float2* F2 = reinterpret_cast<const float2*>(F + (size_t)n * 6);
        float2 f0p = F2[0], f1p = F2[1], f2p = F2[2];

        float f0 = 0.0f, f1 = 0.0f, f2 = 0.0f;
        if (s_VsL >= 0.0f)                    { f0 = f0p.x; f1 = f1p.x; f2 = f2p.x; }
        if (s_VsL < 0.0f && lambdaC > 0.0f)   { f0 = FCL0;  f1 = FCL1;  f2 = FCL2; }
        if (lambdaC <= 0.0f && s_VsR > 0.0f)  { f0 = FCR0;  f1 = FCR1;  f2 = FCR2; }
        if (s_VsR <= 0.0f)                    { f0 = f0p.y; f1 = f1p.y; f2 = f2p.y; }

        out[(size_t)n * 3 + 0] = f0;
        out[(size_t)n * 3 + 1] = f1;
        out[(size_t)n * 3 + 2] = f2;
    }
}

extern "C" void kernel_launch(void* const* d_in, const int* in_sizes, int n_in,
                              void* d_out, int out_size, void* d_ws, size_t ws_size,
                              hipStream_t stream) {
    const float* P  = (const float*)d_in[0];
    // d_in[1] = U (unused), d_in[3] = cmax (unused), d_in[4] = cmin (unused)
    const float* F  = (const float*)d_in[2];
    const float* W1 = (const float*)d_in[5];
    const float* b1 = (const float*)d_in[6];
    const float* W2 = (const float*)d_in[7];
    const float* b2 = (const float*)d_in[8];
    const float* W3 = (const float*)d_in[9];
    const float* b3 = (const float*)d_in[10];
    float* out = (float*)d_out;

    int N = in_sizes[0] / 6;
    int grid = (N + 63) / 64;
    shock_mfma_kernel<<<grid, 64, 0, stream>>>(P, F, W1, b1, W2, b2, W3, b3, out, N);
}